// Round 2
// baseline (305.143 us; speedup 1.0000x reference)
//
#include <hip/hip_runtime.h>

typedef __bf16 bf16;
typedef bf16 bf16x8 __attribute__((ext_vector_type(8)));
typedef float f32x4 __attribute__((ext_vector_type(4)));

#define NB    128
#define NTOK  2048
#define INDIM 256
#define HIDW  128
#define NEXP  8
#define NMODE 4
#define KC    256
#define DC    64
#define NSYM  4096
#define TPBK  2       // 128-token tiles per block -> 8 blocks/batch -> grid 1024

#define RLN2_4 5.770780163555853f   // 4/ln2
#define RLN2_2 2.8853900817779268f  // 2/ln2

// ---------------- Router: LN -> GELU MLP -> expert argmax + power scale (f64, parallel dots) ----
__global__ __launch_bounds__(256)
void router_kernel(const float* __restrict__ phi,
                   const float* __restrict__ ln_g, const float* __restrict__ ln_b,
                   const float* __restrict__ W1, const float* __restrict__ b1,
                   const float* __restrict__ W2, const float* __restrict__ b2,
                   const float* __restrict__ We, const float* __restrict__ be,
                   const float* __restrict__ Wm, const float* __restrict__ bm,
                   float* __restrict__ scale_out, int* __restrict__ eidx_out)
{
  const int b = blockIdx.x, t = threadIdx.x;
  __shared__ double xs[INDIM];
  __shared__ double hs[HIDW];
  __shared__ double part[2][HIDW];
  __shared__ double red4[4];
  __shared__ double lg[NEXP + NMODE];

  // ---- LayerNorm (f64) ----
  double v = (double)phi[b * INDIM + t];
  double s = v;
  #pragma unroll
  for (int off = 32; off; off >>= 1) s += __shfl_down(s, off);
  if ((t & 63) == 0) red4[t >> 6] = s;
  __syncthreads();
  double mu = (red4[0] + red4[1] + red4[2] + red4[3]) * (1.0 / 256.0);
  double dv = v - mu;
  double s2 = dv * dv;
  #pragma unroll
  for (int off = 32; off; off >>= 1) s2 += __shfl_down(s2, off);
  __syncthreads();
  if ((t & 63) == 0) red4[t >> 6] = s2;
  __syncthreads();
  double var = (red4[0] + red4[1] + red4[2] + red4[3]) * (1.0 / 256.0);
  xs[t] = dv * (1.0 / sqrt(var + 1e-5)) * (double)ln_g[t] + (double)ln_b[t];
  __syncthreads();

  const int n = t & 127, h = t >> 7;

  // ---- W1 (256->128): 2 threads per neuron, multi-accumulator ----
  {
    double a0 = 0.0, a1 = 0.0;
    const int i0 = h * 128;
    #pragma unroll 4
    for (int i = 0; i < 128; i += 2) {
      a0 += xs[i0 + i]     * (double)W1[(i0 + i)     * HIDW + n];
      a1 += xs[i0 + i + 1] * (double)W1[(i0 + i + 1) * HIDW + n];
    }
    part[h][n] = a0 + a1;
  }
  __syncthreads();
  if (h == 0) {
    double a = part[0][n] + part[1][n] + (double)b1[n];
    hs[n] = a * 0.5 * (1.0 + erf(a * 0.70710678118654752440));
  }
  __syncthreads();

  // ---- W2 (128->128) ----
  {
    double a0 = 0.0, a1 = 0.0;
    const int i0 = h * 64;
    #pragma unroll 4
    for (int i = 0; i < 64; i += 2) {
      a0 += hs[i0 + i]     * (double)W2[(i0 + i)     * HIDW + n];
      a1 += hs[i0 + i + 1] * (double)W2[(i0 + i + 1) * HIDW + n];
    }
    part[h][n] = a0 + a1;
  }
  __syncthreads();
  double h2v = 0.0;
  if (h == 0) {
    double a = part[0][n] + part[1][n] + (double)b2[n];
    h2v = a * 0.5 * (1.0 + erf(a * 0.70710678118654752440));
  }
  __syncthreads();
  if (h == 0) part[0][n] = h2v;   // reuse part[0] as h2 storage
  __syncthreads();

  // ---- heads: 12 outputs x 128 inputs, 16 lanes per output ----
  if (t < 192) {
    const int g = t >> 4, j = t & 15;
    const float* W; int stride, col; double bias;
    if (g < NEXP) { W = We; stride = NEXP;  col = g;        bias = (double)be[g]; }
    else          { W = Wm; stride = NMODE; col = g - NEXP; bias = (double)bm[g - NEXP]; }
    double a = 0.0;
    #pragma unroll
    for (int i = 0; i < 8; ++i)
      a += part[0][j * 8 + i] * (double)W[(j * 8 + i) * stride + col];
    a += __shfl_down(a, 8);
    a += __shfl_down(a, 4);
    a += __shfl_down(a, 2);
    a += __shfl_down(a, 1);
    if (j == 0) lg[g] = a + bias;
  }
  __syncthreads();
  if (t == 0) {
    int best = 0; double bv = lg[0];
    for (int j = 1; j < NEXP; ++j) if (lg[j] > bv) { bv = lg[j]; best = j; }
    eidx_out[b] = best;
    double m = lg[NEXP];
    for (int j = 1; j < NMODE; ++j) m = fmax(m, lg[NEXP + j]);
    double den = 0.0, num = 0.0;
    for (int j = 0; j < NMODE; ++j) {
      double e = exp(lg[NEXP + j] - m);
      den += e; num += e * (0.25 * (j + 1));
    }
    scale_out[b] = (float)(num / den);
  }
}

// ---------------- Fused VQ, transposed MFMA (codes=M, tokens=N) ----
__global__ __launch_bounds__(256, 4)
void vq_kernel(const float* __restrict__ z, const float* __restrict__ codebooks,
               const float* __restrict__ scale_arr, const int* __restrict__ eidx,
               float* __restrict__ out)
{
  __shared__ __align__(16) bf16 cb_s[KC * DC];   // 32768 B, stride 64, 16B-chunk XOR swizzle
  __shared__ float cn2h_s[KC];                   //  1024 B  (-0.5*||cb_k||^2)
  __shared__ __align__(16) float sb_s[4][32 * 8];//  4096 B  per-wave soft bits

  const int blk  = blockIdx.x;
  const int b    = blk >> 3;
  const int tg   = blk & 7;
  const int tid  = threadIdx.x;
  const int lane = tid & 63;
  const int wid  = tid >> 6;
  const int q    = lane >> 4;
  const int c    = lane & 15;

  // ---- stage codebook: thread = code row, bf16 + chunk swizzle + half-norm ----
  {
    const int e = eidx[b];
    const float* __restrict__ src = codebooks + (size_t)e * KC * DC + tid * DC;
    char* dstrow = (char*)cb_s + tid * 128;
    const int sw = tid & 7;
    float nrm = 0.f;
    #pragma unroll
    for (int j = 0; j < 8; ++j) {
      float4 va = *(const float4*)(src + j * 8);
      float4 vb = *(const float4*)(src + j * 8 + 4);
      bf16x8 p;
      p[0] = (bf16)va.x; p[1] = (bf16)va.y; p[2] = (bf16)va.z; p[3] = (bf16)va.w;
      p[4] = (bf16)vb.x; p[5] = (bf16)vb.y; p[6] = (bf16)vb.z; p[7] = (bf16)vb.w;
      #pragma unroll
      for (int u = 0; u < 8; ++u) { float f = (float)p[u]; nrm += f * f; }
      *(bf16x8*)(dstrow + ((j ^ sw) * 16)) = p;
    }
    cn2h_s[tid] = -0.5f * nrm;
  }
  const float scale_b = scale_arr[b];
  __syncthreads();

  // per-lane LDS A-fragment bases (chunk swizzle folded in)
  const char* pa0 = (const char*)cb_s + c * 128 + ((q    ) ^ (c & 7)) * 16;
  const char* pa1 = (const char*)cb_s + c * 128 + ((q + 4) ^ (c & 7)) * 16;
  const float* __restrict__ cn2q = cn2h_s + q * 4;

  for (int tile = 0; tile < TPBK; ++tile) {
    const int tokw = tg * (TPBK * 128) + tile * 128 + wid * 32;  // wave's 32 tokens

    #pragma unroll
    for (int nt = 0; nt < 2; ++nt) {
      // ---- B fragments: z direct from global (f32 -> bf16) ----
      const float* __restrict__ zt = z + ((size_t)b * NTOK + tokw + nt * 16 + c) * DC + q * 8;
      bf16x8 zb[2];
      #pragma unroll
      for (int ks = 0; ks < 2; ++ks) {
        float4 va = *(const float4*)(zt + ks * 32);
        float4 vb = *(const float4*)(zt + ks * 32 + 4);
        bf16x8 p;
        p[0] = (bf16)va.x; p[1] = (bf16)va.y; p[2] = (bf16)va.z; p[3] = (bf16)va.w;
        p[4] = (bf16)vb.x; p[5] = (bf16)vb.y; p[6] = (bf16)vb.z; p[7] = (bf16)vb.w;
        zb[ks] = p;
      }

      // ---- MFMA: acc[ct][r] = cb.z - 0.5||cb||^2, code = ct*16 + q*4 + r, token = col c ----
      f32x4 acc[16];
      #pragma unroll
      for (int ct = 0; ct < 16; ++ct) {
        f32x4 a = *(const f32x4*)(cn2q + ct * 16);
        bf16x8 a0 = *(const bf16x8*)(pa0 + ct * 2048);
        a = __builtin_amdgcn_mfma_f32_16x16x32_bf16(a0, zb[0], a, 0, 0, 0);
        bf16x8 a1 = *(const bf16x8*)(pa1 + ct * 2048);
        a = __builtin_amdgcn_mfma_f32_16x16x32_bf16(a1, zb[1], a, 0, 0, 0);
        acc[ct] = a;
      }

      // ---- exact max (in-register tree + 2 swizzle stages) ----
      float m0 = -1e30f, m1 = -1e30f, m2 = -1e30f, m3 = -1e30f;
      #pragma unroll
      for (int ct = 0; ct < 16; ++ct) {
        m0 = fmaxf(m0, acc[ct][0]); m1 = fmaxf(m1, acc[ct][1]);
        m2 = fmaxf(m2, acc[ct][2]); m3 = fmaxf(m3, acc[ct][3]);
      }
      float mx = fmaxf(fmaxf(m0, m1), fmaxf(m2, m3));
      mx = fmaxf(mx, __shfl_xor(mx, 16));
      mx = fmaxf(mx, __shfl_xor(mx, 32));
      const float mneg = -mx * RLN2_4;

      // ---- exp + in-register bit-group sums ----
      // label bit j of code k (MSB-first): b0..b3 = ct bits 3..0, b4=(q>=2), b5=(q&1), b6=(r>=2), b7=(r&1)
      float E = 0.f, S0 = 0.f, S1 = 0.f, S2 = 0.f, S3 = 0.f, R0 = 0.f, R1 = 0.f;
      #pragma unroll
      for (int ct = 0; ct < 16; ++ct) {
        float e0 = exp2f(fmaf(acc[ct][0], RLN2_4, mneg));
        float e1 = exp2f(fmaf(acc[ct][1], RLN2_4, mneg));
        float e2 = exp2f(fmaf(acc[ct][2], RLN2_4, mneg));
        float e3 = exp2f(fmaf(acc[ct][3], RLN2_4, mneg));
        float s01 = e0 + e1, s23 = e2 + e3, g = s01 + s23;
        E += g; R0 += s23; R1 += e1 + e3;
        if (ct & 8) S0 += g;
        if (ct & 4) S1 += g;
        if (ct & 2) S2 += g;
        if (ct & 1) S3 += g;
      }

      // ---- cross-q combine: 2-stage butterflies, bit4/bit5 from E intermediates ----
      float Ep = E + __shfl_xor(E, 16);        // q01: E0+E1 ; q23: E2+E3 (= bit4 numer at q>=2)
      float B5 = E + __shfl_xor(E, 32);        // q odd: E1+E3 (= bit5 numer)
      float Et = Ep + __shfl_xor(Ep, 32);      // total
      #define BF2(x) x += __shfl_xor(x, 16); x += __shfl_xor(x, 32);
      BF2(S0) BF2(S1) BF2(S2) BF2(S3) BF2(R0) BF2(R1)
      #undef BF2
      const float rinv = __builtin_amdgcn_rcpf(Et);

      float* row = &sb_s[wid][(nt * 16 + c) * 8];
      float v1 = (q == 0) ? S0 : (q == 1) ? S1 : (q == 2) ? S2 : S3;
      float v2 = (q == 0) ? R0 : (q == 1) ? B5 : (q == 2) ? Ep : R1;
      const int p2 = (q == 3) ? 7 : (6 - q);
      row[q]  = v1 * rinv;
      row[p2] = v2 * rinv;
    }

    // ---- 16-QAM soft demod: lane = (token, symbol), 32 tokens x 2 syms ----
    {
      const int tok = lane >> 1, sym = lane & 1;
      const float* sb = &sb_s[wid][tok * 8 + sym * 4];
      float u0 = sb[0], u1 = sb[1], u2 = sb[2], u3 = sb[3];
      float wsum = 0.f, xa = 0.f, ya = 0.f;
      #pragma unroll
      for (int m = 0; m < 16; ++m) {
        float su = 0.f;
        if (m & 8) su += u0;
        if (m & 4) su += u1;
        if (m & 2) su += u2;
        if (m & 1) su += u3;
        const float pc = (float)__builtin_popcount(m);
        float ev = exp2f(su * RLN2_4 - pc * RLN2_2);
        wsum += ev;
        xa += ev * (float)(2 * (m >> 2) - 3);
        ya += ev * (float)(2 * (m & 3) - 3);
      }
      const float fac = scale_b * 0.23570226039551584f * __builtin_amdgcn_rcpf(wsum);
      const int nidx = tokw + tok;
      float2* op = (float2*)(out + (((size_t)b * NSYM) + 2 * (size_t)nidx + sym) * 2);
      *op = make_float2(xa * fac, ya * fac);
    }
    // no barrier: cb_s is read-only, sb_s is per-wave (wave-synchronous reuse)
  }
}

extern "C" void kernel_launch(void* const* d_in, const int* in_sizes, int n_in,
                              void* d_out, int out_size, void* d_ws, size_t ws_size,
                              hipStream_t stream) {
  const float* phi  = (const float*)d_in[0];
  const float* z    = (const float*)d_in[1];
  const float* ln_g = (const float*)d_in[2];
  const float* ln_b = (const float*)d_in[3];
  const float* W1   = (const float*)d_in[4];
  const float* b1   = (const float*)d_in[5];
  const float* W2   = (const float*)d_in[6];
  const float* b2   = (const float*)d_in[7];
  const float* We   = (const float*)d_in[8];
  const float* be   = (const float*)d_in[9];
  const float* Wm   = (const float*)d_in[10];
  const float* bm   = (const float*)d_in[11];
  const float* cbk  = (const float*)d_in[12];
  float* out   = (float*)d_out;
  float* scale = (float*)d_ws;
  int*   eidx  = (int*)((char*)d_ws + 512);

  router_kernel<<<NB, 256, 0, stream>>>(phi, ln_g, ln_b, W1, b1, W2, b2,
                                        We, be, Wm, bm, scale, eidx);
  vq_kernel<<<NB * 8, 256, 0, stream>>>(z, cbk, scale, eidx, out);
}

// Round 3
// 239.538 us; speedup vs baseline: 1.2739x; 1.2739x over previous
//
#include <hip/hip_runtime.h>

typedef __bf16 bf16;
typedef bf16 bf16x8 __attribute__((ext_vector_type(8)));
typedef float f32x4 __attribute__((ext_vector_type(4)));

#define NB    128
#define NTOK  2048
#define INDIM 256
#define HIDW  128
#define NEXP  8
#define NMODE 4
#define KC    256
#define DC    64
#define NSYM  4096
#define TPBK  2       // 128-token tiles per block -> 8 blocks/batch -> grid 1024

#define RLN2_4 5.770780163555853f   // 4/ln2
#define RLN2_2 2.8853900817779268f  // 2/ln2

// ---------------- Router: LN -> GELU MLP -> expert argmax + power scale (f64, parallel dots) ----
__global__ __launch_bounds__(256)
void router_kernel(const float* __restrict__ phi,
                   const float* __restrict__ ln_g, const float* __restrict__ ln_b,
                   const float* __restrict__ W1, const float* __restrict__ b1,
                   const float* __restrict__ W2, const float* __restrict__ b2,
                   const float* __restrict__ We, const float* __restrict__ be,
                   const float* __restrict__ Wm, const float* __restrict__ bm,
                   float* __restrict__ scale_out, int* __restrict__ eidx_out)
{
  const int b = blockIdx.x, t = threadIdx.x;
  __shared__ double xs[INDIM];
  __shared__ double hs[HIDW];
  __shared__ double part[2][HIDW];
  __shared__ double red4[4];
  __shared__ double lg[NEXP + NMODE];

  // ---- LayerNorm (f64) ----
  double v = (double)phi[b * INDIM + t];
  double s = v;
  #pragma unroll
  for (int off = 32; off; off >>= 1) s += __shfl_down(s, off);
  if ((t & 63) == 0) red4[t >> 6] = s;
  __syncthreads();
  double mu = (red4[0] + red4[1] + red4[2] + red4[3]) * (1.0 / 256.0);
  double dv = v - mu;
  double s2 = dv * dv;
  #pragma unroll
  for (int off = 32; off; off >>= 1) s2 += __shfl_down(s2, off);
  __syncthreads();
  if ((t & 63) == 0) red4[t >> 6] = s2;
  __syncthreads();
  double var = (red4[0] + red4[1] + red4[2] + red4[3]) * (1.0 / 256.0);
  xs[t] = dv * (1.0 / sqrt(var + 1e-5)) * (double)ln_g[t] + (double)ln_b[t];
  __syncthreads();

  const int n = t & 127, h = t >> 7;

  // ---- W1 (256->128): 2 threads per neuron, multi-accumulator ----
  {
    double a0 = 0.0, a1 = 0.0;
    const int i0 = h * 128;
    #pragma unroll 4
    for (int i = 0; i < 128; i += 2) {
      a0 += xs[i0 + i]     * (double)W1[(i0 + i)     * HIDW + n];
      a1 += xs[i0 + i + 1] * (double)W1[(i0 + i + 1) * HIDW + n];
    }
    part[h][n] = a0 + a1;
  }
  __syncthreads();
  if (h == 0) {
    double a = part[0][n] + part[1][n] + (double)b1[n];
    hs[n] = a * 0.5 * (1.0 + erf(a * 0.70710678118654752440));
  }
  __syncthreads();

  // ---- W2 (128->128) ----
  {
    double a0 = 0.0, a1 = 0.0;
    const int i0 = h * 64;
    #pragma unroll 4
    for (int i = 0; i < 64; i += 2) {
      a0 += hs[i0 + i]     * (double)W2[(i0 + i)     * HIDW + n];
      a1 += hs[i0 + i + 1] * (double)W2[(i0 + i + 1) * HIDW + n];
    }
    part[h][n] = a0 + a1;
  }
  __syncthreads();
  double h2v = 0.0;
  if (h == 0) {
    double a = part[0][n] + part[1][n] + (double)b2[n];
    h2v = a * 0.5 * (1.0 + erf(a * 0.70710678118654752440));
  }
  __syncthreads();
  if (h == 0) part[0][n] = h2v;   // reuse part[0] as h2 storage
  __syncthreads();

  // ---- heads: 12 outputs x 128 inputs, 16 lanes per output ----
  if (t < 192) {
    const int g = t >> 4, j = t & 15;
    const float* W; int stride, col; double bias;
    if (g < NEXP) { W = We; stride = NEXP;  col = g;        bias = (double)be[g]; }
    else          { W = Wm; stride = NMODE; col = g - NEXP; bias = (double)bm[g - NEXP]; }
    double a = 0.0;
    #pragma unroll
    for (int i = 0; i < 8; ++i)
      a += part[0][j * 8 + i] * (double)W[(j * 8 + i) * stride + col];
    a += __shfl_down(a, 8);
    a += __shfl_down(a, 4);
    a += __shfl_down(a, 2);
    a += __shfl_down(a, 1);
    if (j == 0) lg[g] = a + bias;
  }
  __syncthreads();
  if (t == 0) {
    int best = 0; double bv = lg[0];
    for (int j = 1; j < NEXP; ++j) if (lg[j] > bv) { bv = lg[j]; best = j; }
    eidx_out[b] = best;
    double m = lg[NEXP];
    for (int j = 1; j < NMODE; ++j) m = fmax(m, lg[NEXP + j]);
    double den = 0.0, num = 0.0;
    for (int j = 0; j < NMODE; ++j) {
      double e = exp(lg[NEXP + j] - m);
      den += e; num += e * (0.25 * (j + 1));
    }
    scale_out[b] = (float)(num / den);
  }
}

// ---------------- Fused VQ, transposed MFMA (codes=M, tokens=N), streamed epilogue ----
// No max-subtraction: logits 4*(z.cb) - 2||cb||^2 are bounded (~±6), exp in f32 is safe,
// softmax ratio is unchanged. This kills the acc[16] live array -> no spills at 4 blocks/CU.
__global__ __launch_bounds__(256, 4)
void vq_kernel(const float* __restrict__ z, const float* __restrict__ codebooks,
               const float* __restrict__ scale_arr, const int* __restrict__ eidx,
               float* __restrict__ out)
{
  __shared__ __align__(16) bf16 cb_s[KC * DC];   // 32768 B, stride 64, 16B-chunk XOR swizzle
  __shared__ float cn2h_s[KC];                   //  1024 B  (-0.5*||cb_k||^2)
  __shared__ __align__(16) float sb_s[4][32 * 8];//  4096 B  per-wave soft bits

  const int blk  = blockIdx.x;
  const int b    = blk >> 3;
  const int tg   = blk & 7;
  const int tid  = threadIdx.x;
  const int lane = tid & 63;
  const int wid  = tid >> 6;
  const int q    = lane >> 4;
  const int c    = lane & 15;

  // ---- stage codebook: thread = code row, bf16 + chunk swizzle + half-norm ----
  {
    const int e = eidx[b];
    const float* __restrict__ src = codebooks + (size_t)e * KC * DC + tid * DC;
    char* dstrow = (char*)cb_s + tid * 128;
    const int sw = tid & 7;
    float nrm = 0.f;
    #pragma unroll
    for (int j = 0; j < 8; ++j) {
      float4 va = *(const float4*)(src + j * 8);
      float4 vb = *(const float4*)(src + j * 8 + 4);
      bf16x8 p;
      p[0] = (bf16)va.x; p[1] = (bf16)va.y; p[2] = (bf16)va.z; p[3] = (bf16)va.w;
      p[4] = (bf16)vb.x; p[5] = (bf16)vb.y; p[6] = (bf16)vb.z; p[7] = (bf16)vb.w;
      #pragma unroll
      for (int u = 0; u < 8; ++u) { float f = (float)p[u]; nrm += f * f; }
      *(bf16x8*)(dstrow + ((j ^ sw) * 16)) = p;
    }
    cn2h_s[tid] = -0.5f * nrm;
  }
  const float scale_b = scale_arr[b];
  __syncthreads();

  // per-lane LDS A-fragment bases (chunk swizzle folded in)
  const char* pa0 = (const char*)cb_s + c * 128 + ((q    ) ^ (c & 7)) * 16;
  const char* pa1 = (const char*)cb_s + c * 128 + ((q + 4) ^ (c & 7)) * 16;
  const float* __restrict__ cn2q = cn2h_s + q * 4;

  for (int tile = 0; tile < TPBK; ++tile) {
    const int tokw = tg * (TPBK * 128) + tile * 128 + wid * 32;  // wave's 32 tokens

    #pragma unroll
    for (int nt = 0; nt < 2; ++nt) {
      // ---- B fragments: z direct from global (f32 -> bf16) ----
      const float* __restrict__ zt = z + ((size_t)b * NTOK + tokw + nt * 16 + c) * DC + q * 8;
      bf16x8 zb[2];
      #pragma unroll
      for (int ks = 0; ks < 2; ++ks) {
        float4 va = *(const float4*)(zt + ks * 32);
        float4 vb = *(const float4*)(zt + ks * 32 + 4);
        bf16x8 p;
        p[0] = (bf16)va.x; p[1] = (bf16)va.y; p[2] = (bf16)va.z; p[3] = (bf16)va.w;
        p[4] = (bf16)vb.x; p[5] = (bf16)vb.y; p[6] = (bf16)vb.z; p[7] = (bf16)vb.w;
        zb[ks] = p;
      }

      // ---- streamed: per code-tile ct, MFMA -> exp2 -> bit-group accumulate ----
      // code = ct*16 + q*4 + r, token = col c
      // label bits (MSB-first): b0..b3 = ct bits 3..0, b4=(q>=2), b5=(q&1), b6=(r>=2), b7=(r&1)
      float E = 0.f, S0 = 0.f, S1 = 0.f, S2 = 0.f, S3 = 0.f, R0 = 0.f, R1 = 0.f;
      #pragma unroll
      for (int ct = 0; ct < 16; ++ct) {
        f32x4 a = *(const f32x4*)(cn2q + ct * 16);
        bf16x8 a0 = *(const bf16x8*)(pa0 + ct * 2048);
        a = __builtin_amdgcn_mfma_f32_16x16x32_bf16(a0, zb[0], a, 0, 0, 0);
        bf16x8 a1 = *(const bf16x8*)(pa1 + ct * 2048);
        a = __builtin_amdgcn_mfma_f32_16x16x32_bf16(a1, zb[1], a, 0, 0, 0);
        float e0 = __builtin_amdgcn_exp2f(a[0] * RLN2_4);
        float e1 = __builtin_amdgcn_exp2f(a[1] * RLN2_4);
        float e2 = __builtin_amdgcn_exp2f(a[2] * RLN2_4);
        float e3 = __builtin_amdgcn_exp2f(a[3] * RLN2_4);
        float s01 = e0 + e1, s23 = e2 + e3, g = s01 + s23;
        E += g; R0 += s23; R1 += e1 + e3;
        if (ct & 8) S0 += g;
        if (ct & 4) S1 += g;
        if (ct & 2) S2 += g;
        if (ct & 1) S3 += g;
      }

      // ---- cross-q combine: 2-stage butterflies, bit4/bit5 from E intermediates ----
      float Ep = E + __shfl_xor(E, 16);        // q01: E0+E1 ; q23: E2+E3 (= bit4 numer at q>=2)
      float B5 = E + __shfl_xor(E, 32);        // q odd: E1+E3 (= bit5 numer)
      float Et = Ep + __shfl_xor(Ep, 32);      // total
      #define BF2(x) x += __shfl_xor(x, 16); x += __shfl_xor(x, 32);
      BF2(S0) BF2(S1) BF2(S2) BF2(S3) BF2(R0) BF2(R1)
      #undef BF2
      const float rinv = __builtin_amdgcn_rcpf(Et);

      float* row = &sb_s[wid][(nt * 16 + c) * 8];
      float v1 = (q == 0) ? S0 : (q == 1) ? S1 : (q == 2) ? S2 : S3;
      float v2 = (q == 0) ? R0 : (q == 1) ? B5 : (q == 2) ? Ep : R1;
      const int p2 = (q == 3) ? 7 : (6 - q);
      row[q]  = v1 * rinv;
      row[p2] = v2 * rinv;
    }

    // ---- 16-QAM soft demod: lane = (token, symbol), 32 tokens x 2 syms ----
    {
      const int tok = lane >> 1, sym = lane & 1;
      const float* sb = &sb_s[wid][tok * 8 + sym * 4];
      float u0 = sb[0], u1 = sb[1], u2 = sb[2], u3 = sb[3];
      float wsum = 0.f, xa = 0.f, ya = 0.f;
      #pragma unroll
      for (int m = 0; m < 16; ++m) {
        float su = 0.f;
        if (m & 8) su += u0;
        if (m & 4) su += u1;
        if (m & 2) su += u2;
        if (m & 1) su += u3;
        const float pc = (float)__builtin_popcount(m);
        float ev = __builtin_amdgcn_exp2f(su * RLN2_4 - pc * RLN2_2);
        wsum += ev;
        xa += ev * (float)(2 * (m >> 2) - 3);
        ya += ev * (float)(2 * (m & 3) - 3);
      }
      const float fac = scale_b * 0.23570226039551584f * __builtin_amdgcn_rcpf(wsum);
      const int nidx = tokw + tok;
      float2* op = (float2*)(out + (((size_t)b * NSYM) + 2 * (size_t)nidx + sym) * 2);
      *op = make_float2(xa * fac, ya * fac);
    }
    // no barrier: cb_s is read-only, sb_s is per-wave (wave-synchronous reuse)
  }
}

extern "C" void kernel_launch(void* const* d_in, const int* in_sizes, int n_in,
                              void* d_out, int out_size, void* d_ws, size_t ws_size,
                              hipStream_t stream) {
  const float* phi  = (const float*)d_in[0];
  const float* z    = (const float*)d_in[1];
  const float* ln_g = (const float*)d_in[2];
  const float* ln_b = (const float*)d_in[3];
  const float* W1   = (const float*)d_in[4];
  const float* b1   = (const float*)d_in[5];
  const float* W2   = (const float*)d_in[6];
  const float* b2   = (const float*)d_in[7];
  const float* We   = (const float*)d_in[8];
  const float* be   = (const float*)d_in[9];
  const float* Wm   = (const float*)d_in[10];
  const float* bm   = (const float*)d_in[11];
  const float* cbk  = (const float*)d_in[12];
  float* out   = (float*)d_out;
  float* scale = (float*)d_ws;
  int*   eidx  = (int*)((char*)d_ws + 512);

  router_kernel<<<NB, 256, 0, stream>>>(phi, ln_g, ln_b, W1, b1, W2, b2,
                                        We, be, Wm, bm, scale, eidx);
  vq_kernel<<<NB * 8, 256, 0, stream>>>(z, cbk, scale, eidx, out);
}

// Round 4
// 144.290 us; speedup vs baseline: 2.1148x; 1.6601x over previous
//
#include <hip/hip_runtime.h>

typedef __bf16 bf16;
typedef bf16 bf16x8 __attribute__((ext_vector_type(8)));
typedef float f32x4 __attribute__((ext_vector_type(4)));

#define NB    128
#define NTOK  2048
#define INDIM 256
#define HIDW  128
#define NEXP  8
#define NMODE 4
#define KC    256
#define DC    64
#define NSYM  4096
#define TPBK  2       // 128-token tiles per block -> 8 blocks/batch -> grid 1024

#define RLN2_4 5.770780163555853f    // 4/ln2
#define RLN2_2 2.8853900817779268f   // 2/ln2
#define NLN2_8 0.0866433975699932f   // ln2/8

// ---------------- Router: LN -> GELU MLP -> expert argmax + power scale (f64, parallel dots) ----
__global__ __launch_bounds__(256)
void router_kernel(const float* __restrict__ phi,
                   const float* __restrict__ ln_g, const float* __restrict__ ln_b,
                   const float* __restrict__ W1, const float* __restrict__ b1,
                   const float* __restrict__ W2, const float* __restrict__ b2,
                   const float* __restrict__ We, const float* __restrict__ be,
                   const float* __restrict__ Wm, const float* __restrict__ bm,
                   float* __restrict__ scale_out, int* __restrict__ eidx_out)
{
  const int b = blockIdx.x, t = threadIdx.x;
  __shared__ double xs[INDIM];
  __shared__ double hs[HIDW];
  __shared__ double part[2][HIDW];
  __shared__ double red4[4];
  __shared__ double lg[NEXP + NMODE];

  // ---- LayerNorm (f64) ----
  double v = (double)phi[b * INDIM + t];
  double s = v;
  #pragma unroll
  for (int off = 32; off; off >>= 1) s += __shfl_down(s, off);
  if ((t & 63) == 0) red4[t >> 6] = s;
  __syncthreads();
  double mu = (red4[0] + red4[1] + red4[2] + red4[3]) * (1.0 / 256.0);
  double dv = v - mu;
  double s2 = dv * dv;
  #pragma unroll
  for (int off = 32; off; off >>= 1) s2 += __shfl_down(s2, off);
  __syncthreads();
  if ((t & 63) == 0) red4[t >> 6] = s2;
  __syncthreads();
  double var = (red4[0] + red4[1] + red4[2] + red4[3]) * (1.0 / 256.0);
  xs[t] = dv * (1.0 / sqrt(var + 1e-5)) * (double)ln_g[t] + (double)ln_b[t];
  __syncthreads();

  const int n = t & 127, h = t >> 7;

  // ---- W1 (256->128): 2 threads per neuron, multi-accumulator ----
  {
    double a0 = 0.0, a1 = 0.0;
    const int i0 = h * 128;
    #pragma unroll 4
    for (int i = 0; i < 128; i += 2) {
      a0 += xs[i0 + i]     * (double)W1[(i0 + i)     * HIDW + n];
      a1 += xs[i0 + i + 1] * (double)W1[(i0 + i + 1) * HIDW + n];
    }
    part[h][n] = a0 + a1;
  }
  __syncthreads();
  if (h == 0) {
    double a = part[0][n] + part[1][n] + (double)b1[n];
    hs[n] = a * 0.5 * (1.0 + erf(a * 0.70710678118654752440));
  }
  __syncthreads();

  // ---- W2 (128->128) ----
  {
    double a0 = 0.0, a1 = 0.0;
    const int i0 = h * 64;
    #pragma unroll 4
    for (int i = 0; i < 64; i += 2) {
      a0 += hs[i0 + i]     * (double)W2[(i0 + i)     * HIDW + n];
      a1 += hs[i0 + i + 1] * (double)W2[(i0 + i + 1) * HIDW + n];
    }
    part[h][n] = a0 + a1;
  }
  __syncthreads();
  double h2v = 0.0;
  if (h == 0) {
    double a = part[0][n] + part[1][n] + (double)b2[n];
    h2v = a * 0.5 * (1.0 + erf(a * 0.70710678118654752440));
  }
  __syncthreads();
  if (h == 0) part[0][n] = h2v;   // reuse part[0] as h2 storage
  __syncthreads();

  // ---- heads: 12 outputs x 128 inputs, 16 lanes per output ----
  if (t < 192) {
    const int g = t >> 4, j = t & 15;
    const float* W; int stride, col; double bias;
    if (g < NEXP) { W = We; stride = NEXP;  col = g;        bias = (double)be[g]; }
    else          { W = Wm; stride = NMODE; col = g - NEXP; bias = (double)bm[g - NEXP]; }
    double a = 0.0;
    #pragma unroll
    for (int i = 0; i < 8; ++i)
      a += part[0][j * 8 + i] * (double)W[(j * 8 + i) * stride + col];
    a += __shfl_down(a, 8);
    a += __shfl_down(a, 4);
    a += __shfl_down(a, 2);
    a += __shfl_down(a, 1);
    if (j == 0) lg[g] = a + bias;
  }
  __syncthreads();
  if (t == 0) {
    int best = 0; double bv = lg[0];
    for (int j = 1; j < NEXP; ++j) if (lg[j] > bv) { bv = lg[j]; best = j; }
    eidx_out[b] = best;
    double m = lg[NEXP];
    for (int j = 1; j < NMODE; ++j) m = fmax(m, lg[NEXP + j]);
    double den = 0.0, num = 0.0;
    for (int j = 0; j < NMODE; ++j) {
      double e = exp(lg[NEXP + j] - m);
      den += e; num += e * (0.25 * (j + 1));
    }
    scale_out[b] = (float)(num / den);
  }
}

// ---------------- Fused VQ, transposed MFMA (codes=M, tokens=N), streamed + spill-proofed ----
// Codebook pre-scaled by 4/ln2 so MFMA output IS the exp2 argument:
//   acc = (4/ln2)*z.cb - (2/ln2)*||cb||^2  ->  e = exp2(acc)   (no max-subtraction; logits ~±9)
// ct loop chunked with sched_barrier(0) to bound LDS-load hoisting; (256,3) -> ~170 reg cap.
__global__ __launch_bounds__(256, 3)
void vq_kernel(const float* __restrict__ z, const float* __restrict__ codebooks,
               const float* __restrict__ scale_arr, const int* __restrict__ eidx,
               float* __restrict__ out)
{
  __shared__ __align__(16) bf16 cb_s[KC * DC];   // 32768 B, stride 64, 16B-chunk XOR swizzle
  __shared__ float cn2h_s[KC];                   //  1024 B  (-(ln2/8)*sum(cbs^2))
  __shared__ __align__(16) float sb_s[4][32 * 8];//  4096 B  per-wave soft bits

  const int blk  = blockIdx.x;
  const int b    = blk >> 3;
  const int tg   = blk & 7;
  const int tid  = threadIdx.x;
  const int lane = tid & 63;
  const int wid  = tid >> 6;
  const int q    = lane >> 4;
  const int c    = lane & 15;

  // ---- stage codebook: thread = code row, bf16(cb*4/ln2) + chunk swizzle + norm ----
  {
    const int e = eidx[b];
    const float* __restrict__ src = codebooks + (size_t)e * KC * DC + tid * DC;
    char* dstrow = (char*)cb_s + tid * 128;
    const int sw = tid & 7;
    float nrm = 0.f;
    #pragma unroll
    for (int j = 0; j < 8; ++j) {
      float4 va = *(const float4*)(src + j * 8);
      float4 vb = *(const float4*)(src + j * 8 + 4);
      bf16x8 p;
      p[0] = (bf16)(va.x * RLN2_4); p[1] = (bf16)(va.y * RLN2_4);
      p[2] = (bf16)(va.z * RLN2_4); p[3] = (bf16)(va.w * RLN2_4);
      p[4] = (bf16)(vb.x * RLN2_4); p[5] = (bf16)(vb.y * RLN2_4);
      p[6] = (bf16)(vb.z * RLN2_4); p[7] = (bf16)(vb.w * RLN2_4);
      #pragma unroll
      for (int u = 0; u < 8; ++u) { float f = (float)p[u]; nrm += f * f; }
      *(bf16x8*)(dstrow + ((j ^ sw) * 16)) = p;
    }
    cn2h_s[tid] = -NLN2_8 * nrm;
  }
  const float scale_b = scale_arr[b];
  __syncthreads();

  // per-lane LDS A-fragment bases (chunk swizzle folded in)
  const char* pa0 = (const char*)cb_s + c * 128 + ((q    ) ^ (c & 7)) * 16;
  const char* pa1 = (const char*)cb_s + c * 128 + ((q + 4) ^ (c & 7)) * 16;
  const float* __restrict__ cn2q = cn2h_s + q * 4;

  for (int tile = 0; tile < TPBK; ++tile) {
    const int tokw = tg * (TPBK * 128) + tile * 128 + wid * 32;  // wave's 32 tokens

    #pragma unroll
    for (int nt = 0; nt < 2; ++nt) {
      // ---- B fragments: z direct from global (f32 -> bf16) ----
      const float* __restrict__ zt = z + ((size_t)b * NTOK + tokw + nt * 16 + c) * DC + q * 8;
      bf16x8 zb[2];
      #pragma unroll
      for (int ks = 0; ks < 2; ++ks) {
        float4 va = *(const float4*)(zt + ks * 32);
        float4 vb = *(const float4*)(zt + ks * 32 + 4);
        bf16x8 p;
        p[0] = (bf16)va.x; p[1] = (bf16)va.y; p[2] = (bf16)va.z; p[3] = (bf16)va.w;
        p[4] = (bf16)vb.x; p[5] = (bf16)vb.y; p[6] = (bf16)vb.z; p[7] = (bf16)vb.w;
        zb[ks] = p;
      }

      // ---- streamed: per code-tile ct, MFMA -> exp2 -> bit-group accumulate ----
      // code = ct*16 + q*4 + r, token = col c
      // label bits (MSB-first): b0..b3 = ct bits 3..0, b4=(q>=2), b5=(q&1), b6=(r>=2), b7=(r&1)
      float E = 0.f, S0 = 0.f, S1 = 0.f, S2 = 0.f, S3 = 0.f, R0 = 0.f, R1 = 0.f;
      #pragma unroll
      for (int cc = 0; cc < 4; ++cc) {
        #pragma unroll
        for (int ci = 0; ci < 4; ++ci) {
          const int ct = cc * 4 + ci;
          f32x4 a = *(const f32x4*)(cn2q + ct * 16);
          bf16x8 a0 = *(const bf16x8*)(pa0 + ct * 2048);
          a = __builtin_amdgcn_mfma_f32_16x16x32_bf16(a0, zb[0], a, 0, 0, 0);
          bf16x8 a1 = *(const bf16x8*)(pa1 + ct * 2048);
          a = __builtin_amdgcn_mfma_f32_16x16x32_bf16(a1, zb[1], a, 0, 0, 0);
          float e0 = __builtin_amdgcn_exp2f(a[0]);
          float e1 = __builtin_amdgcn_exp2f(a[1]);
          float e2 = __builtin_amdgcn_exp2f(a[2]);
          float e3 = __builtin_amdgcn_exp2f(a[3]);
          float s01 = e0 + e1, s23 = e2 + e3, g = s01 + s23;
          E += g; R0 += s23; R1 += e1 + e3;
          if (ct & 8) S0 += g;
          if (ct & 4) S1 += g;
          if (ct & 2) S2 += g;
          if (ct & 1) S3 += g;
        }
        __builtin_amdgcn_sched_barrier(0);   // bound load-hoisting window -> no spills
      }

      // ---- cross-q combine: 2-stage butterflies, bit4/bit5 from E intermediates ----
      float Ep = E + __shfl_xor(E, 16);        // q01: E0+E1 ; q23: E2+E3 (= bit4 numer at q>=2)
      float B5 = E + __shfl_xor(E, 32);        // q odd: E1+E3 (= bit5 numer)
      float Et = Ep + __shfl_xor(Ep, 32);      // total
      #define BF2(x) x += __shfl_xor(x, 16); x += __shfl_xor(x, 32);
      BF2(S0) BF2(S1) BF2(S2) BF2(S3) BF2(R0) BF2(R1)
      #undef BF2
      const float rinv = __builtin_amdgcn_rcpf(Et);

      float* row = &sb_s[wid][(nt * 16 + c) * 8];
      float v1 = (q == 0) ? S0 : (q == 1) ? S1 : (q == 2) ? S2 : S3;
      float v2 = (q == 0) ? R0 : (q == 1) ? B5 : (q == 2) ? Ep : R1;
      const int p2 = (q == 3) ? 7 : (6 - q);
      row[q]  = v1 * rinv;
      row[p2] = v2 * rinv;
    }

    // ---- 16-QAM soft demod: lane = (token, symbol), 32 tokens x 2 syms ----
    {
      const int tok = lane >> 1, sym = lane & 1;
      const float* sb = &sb_s[wid][tok * 8 + sym * 4];
      float u0 = sb[0], u1 = sb[1], u2 = sb[2], u3 = sb[3];
      float wsum = 0.f, xa = 0.f, ya = 0.f;
      #pragma unroll
      for (int m = 0; m < 16; ++m) {
        float su = 0.f;
        if (m & 8) su += u0;
        if (m & 4) su += u1;
        if (m & 2) su += u2;
        if (m & 1) su += u3;
        const float pc = (float)__builtin_popcount(m);
        float ev = __builtin_amdgcn_exp2f(su * RLN2_4 - pc * RLN2_2);
        wsum += ev;
        xa += ev * (float)(2 * (m >> 2) - 3);
        ya += ev * (float)(2 * (m & 3) - 3);
      }
      const float fac = scale_b * 0.23570226039551584f * __builtin_amdgcn_rcpf(wsum);
      const int nidx = tokw + tok;
      float2* op = (float2*)(out + (((size_t)b * NSYM) + 2 * (size_t)nidx + sym) * 2);
      *op = make_float2(xa * fac, ya * fac);
    }
    // no barrier: cb_s is read-only, sb_s is per-wave (wave-synchronous reuse)
  }
}

extern "C" void kernel_launch(void* const* d_in, const int* in_sizes, int n_in,
                              void* d_out, int out_size, void* d_ws, size_t ws_size,
                              hipStream_t stream) {
  const float* phi  = (const float*)d_in[0];
  const float* z    = (const float*)d_in[1];
  const float* ln_g = (const float*)d_in[2];
  const float* ln_b = (const float*)d_in[3];
  const float* W1   = (const float*)d_in[4];
  const float* b1   = (const float*)d_in[5];
  const float* W2   = (const float*)d_in[6];
  const float* b2   = (const float*)d_in[7];
  const float* We   = (const float*)d_in[8];
  const float* be   = (const float*)d_in[9];
  const float* Wm   = (const float*)d_in[10];
  const float* bm   = (const float*)d_in[11];
  const float* cbk  = (const float*)d_in[12];
  float* out   = (float*)d_out;
  float* scale = (float*)d_ws;
  int*   eidx  = (int*)((char*)d_ws + 512);

  router_kernel<<<NB, 256, 0, stream>>>(phi, ln_g, ln_b, W1, b1, W2, b2,
                                        We, be, Wm, bm, scale, eidx);
  vq_kernel<<<NB * 8, 256, 0, stream>>>(z, cbk, scale, eidx, out);
}

// Round 5
// 141.432 us; speedup vs baseline: 2.1575x; 1.0202x over previous
//
#include <hip/hip_runtime.h>

typedef __bf16 bf16;
typedef bf16 bf16x8 __attribute__((ext_vector_type(8)));
typedef float f32x4 __attribute__((ext_vector_type(4)));

#define NB    128
#define NTOK  2048
#define INDIM 256
#define HIDW  128
#define NEXP  8
#define NMODE 4
#define KC    256
#define DC    64
#define NSYM  4096
#define TPBK  2       // 128-token tiles per block -> 8 blocks/batch -> grid 1024

#define RLN2_4 5.770780163555853f    // 4/ln2
#define RLN2_2 2.8853900817779268f   // 2/ln2
#define NLN2_8 0.0866433975699932f   // ln2/8

// ---------------- Router: LN -> GELU MLP -> expert argmax + power scale (f64, parallel dots) ----
__global__ __launch_bounds__(256)
void router_kernel(const float* __restrict__ phi,
                   const float* __restrict__ ln_g, const float* __restrict__ ln_b,
                   const float* __restrict__ W1, const float* __restrict__ b1,
                   const float* __restrict__ W2, const float* __restrict__ b2,
                   const float* __restrict__ We, const float* __restrict__ be,
                   const float* __restrict__ Wm, const float* __restrict__ bm,
                   float* __restrict__ scale_out, int* __restrict__ eidx_out)
{
  const int b = blockIdx.x, t = threadIdx.x;
  __shared__ double xs[INDIM];
  __shared__ double hs[HIDW];
  __shared__ double part[2][HIDW];
  __shared__ double red4[4];
  __shared__ double lg[NEXP + NMODE];

  // ---- LayerNorm (f64) ----
  double v = (double)phi[b * INDIM + t];
  double s = v;
  #pragma unroll
  for (int off = 32; off; off >>= 1) s += __shfl_down(s, off);
  if ((t & 63) == 0) red4[t >> 6] = s;
  __syncthreads();
  double mu = (red4[0] + red4[1] + red4[2] + red4[3]) * (1.0 / 256.0);
  double dv = v - mu;
  double s2 = dv * dv;
  #pragma unroll
  for (int off = 32; off; off >>= 1) s2 += __shfl_down(s2, off);
  __syncthreads();
  if ((t & 63) == 0) red4[t >> 6] = s2;
  __syncthreads();
  double var = (red4[0] + red4[1] + red4[2] + red4[3]) * (1.0 / 256.0);
  xs[t] = dv * (1.0 / sqrt(var + 1e-5)) * (double)ln_g[t] + (double)ln_b[t];
  __syncthreads();

  const int n = t & 127, h = t >> 7;

  // ---- W1 (256->128): 2 threads per neuron, multi-accumulator ----
  {
    double a0 = 0.0, a1 = 0.0;
    const int i0 = h * 128;
    #pragma unroll 4
    for (int i = 0; i < 128; i += 2) {
      a0 += xs[i0 + i]     * (double)W1[(i0 + i)     * HIDW + n];
      a1 += xs[i0 + i + 1] * (double)W1[(i0 + i + 1) * HIDW + n];
    }
    part[h][n] = a0 + a1;
  }
  __syncthreads();
  if (h == 0) {
    double a = part[0][n] + part[1][n] + (double)b1[n];
    hs[n] = a * 0.5 * (1.0 + erf(a * 0.70710678118654752440));
  }
  __syncthreads();

  // ---- W2 (128->128) ----
  {
    double a0 = 0.0, a1 = 0.0;
    const int i0 = h * 64;
    #pragma unroll 4
    for (int i = 0; i < 64; i += 2) {
      a0 += hs[i0 + i]     * (double)W2[(i0 + i)     * HIDW + n];
      a1 += hs[i0 + i + 1] * (double)W2[(i0 + i + 1) * HIDW + n];
    }
    part[h][n] = a0 + a1;
  }
  __syncthreads();
  double h2v = 0.0;
  if (h == 0) {
    double a = part[0][n] + part[1][n] + (double)b2[n];
    h2v = a * 0.5 * (1.0 + erf(a * 0.70710678118654752440));
  }
  __syncthreads();
  if (h == 0) part[0][n] = h2v;   // reuse part[0] as h2 storage
  __syncthreads();

  // ---- heads: 12 outputs x 128 inputs, 16 lanes per output ----
  if (t < 192) {
    const int g = t >> 4, j = t & 15;
    const float* W; int stride, col; double bias;
    if (g < NEXP) { W = We; stride = NEXP;  col = g;        bias = (double)be[g]; }
    else          { W = Wm; stride = NMODE; col = g - NEXP; bias = (double)bm[g - NEXP]; }
    double a = 0.0;
    #pragma unroll
    for (int i = 0; i < 8; ++i)
      a += part[0][j * 8 + i] * (double)W[(j * 8 + i) * stride + col];
    a += __shfl_down(a, 8);
    a += __shfl_down(a, 4);
    a += __shfl_down(a, 2);
    a += __shfl_down(a, 1);
    if (j == 0) lg[g] = a + bias;
  }
  __syncthreads();
  if (t == 0) {
    int best = 0; double bv = lg[0];
    for (int j = 1; j < NEXP; ++j) if (lg[j] > bv) { bv = lg[j]; best = j; }
    eidx_out[b] = best;
    double m = lg[NEXP];
    for (int j = 1; j < NMODE; ++j) m = fmax(m, lg[NEXP + j]);
    double den = 0.0, num = 0.0;
    for (int j = 0; j < NMODE; ++j) {
      double e = exp(lg[NEXP + j] - m);
      den += e; num += e * (0.25 * (j + 1));
    }
    scale_out[b] = (float)(num / den);
  }
}

// ---------------- Fused VQ, transposed MFMA (codes=M, tokens=N) ----
// Merged nt-pair inner loop: each LDS (C, a0, a1) triple feeds 4 MFMAs (both
// 16-token groups) -> LDS b128 traffic halved vs per-nt loop (192 -> 96/wave).
// Codebook pre-scaled by 4/ln2 so MFMA output IS the exp2 argument; no
// max-subtraction (logits bounded ~±9, f32-exact softmax ratio).
__global__ __launch_bounds__(256, 3)
void vq_kernel(const float* __restrict__ z, const float* __restrict__ codebooks,
               const float* __restrict__ scale_arr, const int* __restrict__ eidx,
               float* __restrict__ out)
{
  __shared__ __align__(16) bf16 cb_s[KC * DC];   // 32768 B, stride 64, 16B-chunk XOR swizzle
  __shared__ float cn2h_s[KC];                   //  1024 B  (-(ln2/8)*sum(cbs^2))
  __shared__ __align__(16) float sb_s[4][32 * 8];//  4096 B  per-wave soft bits

  const int blk  = blockIdx.x;
  const int b    = blk >> 3;
  const int tg   = blk & 7;
  const int tid  = threadIdx.x;
  const int lane = tid & 63;
  const int wid  = tid >> 6;
  const int q    = lane >> 4;
  const int c    = lane & 15;

  // ---- stage codebook: thread = code row, bf16(cb*4/ln2) + chunk swizzle + norm ----
  {
    const int e = eidx[b];
    const float* __restrict__ src = codebooks + (size_t)e * KC * DC + tid * DC;
    char* dstrow = (char*)cb_s + tid * 128;
    const int sw = tid & 7;
    float nrm = 0.f;
    #pragma unroll
    for (int j = 0; j < 8; ++j) {
      float4 va = *(const float4*)(src + j * 8);
      float4 vb = *(const float4*)(src + j * 8 + 4);
      bf16x8 p;
      p[0] = (bf16)(va.x * RLN2_4); p[1] = (bf16)(va.y * RLN2_4);
      p[2] = (bf16)(va.z * RLN2_4); p[3] = (bf16)(va.w * RLN2_4);
      p[4] = (bf16)(vb.x * RLN2_4); p[5] = (bf16)(vb.y * RLN2_4);
      p[6] = (bf16)(vb.z * RLN2_4); p[7] = (bf16)(vb.w * RLN2_4);
      #pragma unroll
      for (int u = 0; u < 8; ++u) { float f = (float)p[u]; nrm += f * f; }
      *(bf16x8*)(dstrow + ((j ^ sw) * 16)) = p;
    }
    cn2h_s[tid] = -NLN2_8 * nrm;
  }
  const float scale_b = scale_arr[b];
  __syncthreads();

  // per-lane LDS A-fragment bases (chunk swizzle folded in)
  const char* pa0 = (const char*)cb_s + c * 128 + ((q    ) ^ (c & 7)) * 16;
  const char* pa1 = (const char*)cb_s + c * 128 + ((q + 4) ^ (c & 7)) * 16;
  const float* __restrict__ cn2q = cn2h_s + q * 4;

  for (int tile = 0; tile < TPBK; ++tile) {
    const int tokw = tg * (TPBK * 128) + tile * 128 + wid * 32;  // wave's 32 tokens

    // ---- B fragments for BOTH 16-token groups: z direct from global (f32 -> bf16) ----
    bf16x8 zb[2][2];   // [nt][ks]
    #pragma unroll
    for (int nt = 0; nt < 2; ++nt) {
      const float* __restrict__ zt = z + ((size_t)b * NTOK + tokw + nt * 16 + c) * DC + q * 8;
      #pragma unroll
      for (int ks = 0; ks < 2; ++ks) {
        float4 va = *(const float4*)(zt + ks * 32);
        float4 vb = *(const float4*)(zt + ks * 32 + 4);
        bf16x8 p;
        p[0] = (bf16)va.x; p[1] = (bf16)va.y; p[2] = (bf16)va.z; p[3] = (bf16)va.w;
        p[4] = (bf16)vb.x; p[5] = (bf16)vb.y; p[6] = (bf16)vb.z; p[7] = (bf16)vb.w;
        zb[nt][ks] = p;
      }
    }

    // ---- streamed: per code-tile ct, 1 C + 2 A reads feed 4 MFMAs (both nt) ----
    // code = ct*16 + q*4 + r, token = col c (+ nt*16)
    // label bits (MSB-first): b0..b3 = ct bits 3..0, b4=(q>=2), b5=(q&1), b6=(r>=2), b7=(r&1)
    float E[2]  = {0.f, 0.f}, S0[2] = {0.f, 0.f}, S1[2] = {0.f, 0.f},
          S2[2] = {0.f, 0.f}, S3[2] = {0.f, 0.f}, R0[2] = {0.f, 0.f}, R1[2] = {0.f, 0.f};
    #pragma unroll
    for (int cc = 0; cc < 4; ++cc) {
      #pragma unroll
      for (int ci = 0; ci < 4; ++ci) {
        const int ct = cc * 4 + ci;
        f32x4 cinit = *(const f32x4*)(cn2q + ct * 16);
        bf16x8 a0 = *(const bf16x8*)(pa0 + ct * 2048);
        bf16x8 a1 = *(const bf16x8*)(pa1 + ct * 2048);
        #pragma unroll
        for (int nt = 0; nt < 2; ++nt) {
          f32x4 a = __builtin_amdgcn_mfma_f32_16x16x32_bf16(a0, zb[nt][0], cinit, 0, 0, 0);
          a = __builtin_amdgcn_mfma_f32_16x16x32_bf16(a1, zb[nt][1], a, 0, 0, 0);
          float e0 = __builtin_amdgcn_exp2f(a[0]);
          float e1 = __builtin_amdgcn_exp2f(a[1]);
          float e2 = __builtin_amdgcn_exp2f(a[2]);
          float e3 = __builtin_amdgcn_exp2f(a[3]);
          float s01 = e0 + e1, s23 = e2 + e3, g = s01 + s23;
          E[nt] += g; R0[nt] += s23; R1[nt] += e1 + e3;
          if (ct & 8) S0[nt] += g;
          if (ct & 4) S1[nt] += g;
          if (ct & 2) S2[nt] += g;
          if (ct & 1) S3[nt] += g;
        }
      }
      __builtin_amdgcn_sched_barrier(0);   // bound load-hoisting window -> no spills
    }

    // ---- cross-q combine: 2-stage butterflies, bit4/bit5 from E intermediates ----
    #pragma unroll
    for (int nt = 0; nt < 2; ++nt) {
      float En = E[nt];
      float Ep = En + __shfl_xor(En, 16);      // q01: E0+E1 ; q23: E2+E3 (= bit4 numer at q>=2)
      float B5 = En + __shfl_xor(En, 32);      // q odd: E1+E3 (= bit5 numer)
      float Et = Ep + __shfl_xor(Ep, 32);      // total
      float s0 = S0[nt], s1 = S1[nt], s2 = S2[nt], s3 = S3[nt], r0 = R0[nt], r1 = R1[nt];
      #define BF2(x) x += __shfl_xor(x, 16); x += __shfl_xor(x, 32);
      BF2(s0) BF2(s1) BF2(s2) BF2(s3) BF2(r0) BF2(r1)
      #undef BF2
      const float rinv = __builtin_amdgcn_rcpf(Et);

      float* row = &sb_s[wid][(nt * 16 + c) * 8];
      float v1 = (q == 0) ? s0 : (q == 1) ? s1 : (q == 2) ? s2 : s3;
      float v2 = (q == 0) ? r0 : (q == 1) ? B5 : (q == 2) ? Ep : r1;
      const int p2 = (q == 3) ? 7 : (6 - q);
      row[q]  = v1 * rinv;
      row[p2] = v2 * rinv;
    }

    // ---- 16-QAM soft demod: lane = (token, symbol), 32 tokens x 2 syms ----
    {
      const int tok = lane >> 1, sym = lane & 1;
      const float* sb = &sb_s[wid][tok * 8 + sym * 4];
      float u0 = sb[0], u1 = sb[1], u2 = sb[2], u3 = sb[3];
      float wsum = 0.f, xa = 0.f, ya = 0.f;
      #pragma unroll
      for (int m = 0; m < 16; ++m) {
        float su = 0.f;
        if (m & 8) su += u0;
        if (m & 4) su += u1;
        if (m & 2) su += u2;
        if (m & 1) su += u3;
        const float pc = (float)__builtin_popcount(m);
        float ev = __builtin_amdgcn_exp2f(su * RLN2_4 - pc * RLN2_2);
        wsum += ev;
        xa += ev * (float)(2 * (m >> 2) - 3);
        ya += ev * (float)(2 * (m & 3) - 3);
      }
      const float fac = scale_b * 0.23570226039551584f * __builtin_amdgcn_rcpf(wsum);
      const int nidx = tokw + tok;
      float2* op = (float2*)(out + (((size_t)b * NSYM) + 2 * (size_t)nidx + sym) * 2);
      *op = make_float2(xa * fac, ya * fac);
    }
    // no barrier: cb_s is read-only, sb_s is per-wave (wave-synchronous reuse)
  }
}

extern "C" void kernel_launch(void* const* d_in, const int* in_sizes, int n_in,
                              void* d_out, int out_size, void* d_ws, size_t ws_size,
                              hipStream_t stream) {
  const float* phi  = (const float*)d_in[0];
  const float* z    = (const float*)d_in[1];
  const float* ln_g = (const float*)d_in[2];
  const float* ln_b = (const float*)d_in[3];
  const float* W1   = (const float*)d_in[4];
  const float* b1   = (const float*)d_in[5];
  const float* W2   = (const float*)d_in[6];
  const float* b2   = (const float*)d_in[7];
  const float* We   = (const float*)d_in[8];
  const float* be   = (const float*)d_in[9];
  const float* Wm   = (const float*)d_in[10];
  const float* bm   = (const float*)d_in[11];
  const float* cbk  = (const float*)d_in[12];
  float* out   = (float*)d_out;
  float* scale = (float*)d_ws;
  int*   eidx  = (int*)((char*)d_ws + 512);

  router_kernel<<<NB, 256, 0, stream>>>(phi, ln_g, ln_b, W1, b1, W2, b2,
                                        We, be, Wm, bm, scale, eidx);
  vq_kernel<<<NB * 8, 256, 0, stream>>>(z, cbk, scale, eidx, out);
}